// Round 6
// baseline (70.905 us; speedup 1.0000x reference)
//
#include <hip/hip_runtime.h>
#include <math.h>

#define DD 1024
#define HD 128
#define BI 64
#define RR 36
#define BC 32
#define TT 64

#define EPS_BN 1e-5f
#define EPS_L2 1e-8f
#define GAMMA_SM 10.0f
#define LOG2E 1.44269504088896f

// ============ K1: per-caption pool+l2norm (blocks 0..31)
//              | direct BN mean/rstd, 32 d-channels/block (blocks 32..63) ===
__global__ __launch_bounds__(256) void kP(const float* __restrict__ cap,
                                          const int* __restrict__ lens,
                                          const float* __restrict__ img,
                                          float* __restrict__ repr,
                                          float* __restrict__ capn,
                                          float* __restrict__ meanp,
                                          float* __restrict__ rstdp) {
    int bid = blockIdx.x, tid = threadIdx.x;
    __shared__ float4 ls[256];
    __shared__ float4 lq[256];
    if (bid < 32) {
        int c = bid;
        int len = lens[c];
        const float4* p = reinterpret_cast<const float4*>(cap + (size_t)c * TT * DD) + tid;
        float4 s = {0.f, 0.f, 0.f, 0.f};
        for (int t = 0; t < len; t++) {
            float4 x = p[(size_t)t * 256];
            s.x += x.x; s.y += x.y; s.z += x.z; s.w += x.w;
        }
        float inv = 1.0f / (float)len;
        float4 v = {s.x * inv, s.y * inv, s.z * inv, s.w * inv};
        reinterpret_cast<float4*>(repr)[c * 256 + tid] = v;
        float* red = reinterpret_cast<float*>(ls);
        red[tid] = fmaf(v.x, v.x, fmaf(v.y, v.y, fmaf(v.z, v.z, v.w * v.w)));
        __syncthreads();
        for (int st = 128; st > 0; st >>= 1) {
            if (tid < st) red[tid] += red[tid + st];
            __syncthreads();
        }
        float invn = 1.0f / (sqrtf(red[0]) + EPS_L2);
        float4 o = {v.x * invn, v.y * invn, v.z * invn, v.w * invn};
        reinterpret_cast<float4*>(capn)[c * 256 + tid] = o;
    } else {
        // block owns d-channels [j*32, j*32+32): no cross-block reduction
        int j = bid - 32;                 // 0..31
        int w = tid & 7;                  // float4-column within chunk
        int rg = tid >> 3;                // 0..31 row-group
        const float4* ip = reinterpret_cast<const float4*>(img) + (size_t)j * 8 + w;
        float4 s = {0.f, 0.f, 0.f, 0.f}, q = {0.f, 0.f, 0.f, 0.f};
        for (int r = rg; r < BI * RR; r += 32) {
            float4 x = ip[(size_t)r * 256];
            s.x += x.x; s.y += x.y; s.z += x.z; s.w += x.w;
            q.x = fmaf(x.x, x.x, q.x); q.y = fmaf(x.y, x.y, q.y);
            q.z = fmaf(x.z, x.z, q.z); q.w = fmaf(x.w, x.w, q.w);
        }
        ls[tid] = s; lq[tid] = q;
        __syncthreads();
        if (tid < 64) {   // fold rg 8..31 into rg 0..7
#pragma unroll
            for (int k = 1; k < 4; k++) {
                float4 a = ls[tid + k * 64], b = lq[tid + k * 64];
                ls[tid].x += a.x; ls[tid].y += a.y; ls[tid].z += a.z; ls[tid].w += a.w;
                lq[tid].x += b.x; lq[tid].y += b.y; lq[tid].z += b.z; lq[tid].w += b.w;
            }
        }
        __syncthreads();
        if (tid < 8) {
            float4 ss = {0.f, 0.f, 0.f, 0.f}, qq = {0.f, 0.f, 0.f, 0.f};
#pragma unroll
            for (int k = 0; k < 8; k++) {
                float4 a = ls[k * 8 + tid], b = lq[k * 8 + tid];
                ss.x += a.x; ss.y += a.y; ss.z += a.z; ss.w += a.w;
                qq.x += b.x; qq.y += b.y; qq.z += b.z; qq.w += b.w;
            }
            const float invN = 1.0f / (float)(BI * RR);
            float4 m = {ss.x * invN, ss.y * invN, ss.z * invN, ss.w * invN};
            float4 rs;
            rs.x = rsqrtf(fmaf(-m.x, m.x, qq.x * invN) + EPS_BN);
            rs.y = rsqrtf(fmaf(-m.y, m.y, qq.y * invN) + EPS_BN);
            rs.z = rsqrtf(fmaf(-m.z, m.z, qq.z * invN) + EPS_BN);
            rs.w = rsqrtf(fmaf(-m.w, m.w, qq.w * invN) + EPS_BN);
            reinterpret_cast<float4*>(meanp)[j * 8 + tid] = m;
            reinterpret_cast<float4*>(rstdp)[j * 8 + tid] = rs;
        }
    }
}

// ============ K2: full MLP per (caption, branch) block; 64 blocks =========
// layer1: 8-way k-split, thread=(kh, w) covers h4=w*4; layer2: float4 over d
__global__ __launch_bounds__(256) void kM(const float* __restrict__ repr,
                                          const float* __restrict__ Wg1,
                                          const float* __restrict__ bg1,
                                          const float* __restrict__ Wg2,
                                          const float* __restrict__ bg2,
                                          const float* __restrict__ Wb1,
                                          const float* __restrict__ bb1,
                                          const float* __restrict__ Wb2,
                                          const float* __restrict__ bb2,
                                          float* __restrict__ gamma,
                                          float* __restrict__ beta) {
    int c = blockIdx.x >> 1, gb = blockIdx.x & 1;
    int tid = threadIdx.x;
    const float4* W1 = reinterpret_cast<const float4*>(gb ? Wb1 : Wg1);
    const float4* B1 = reinterpret_cast<const float4*>(gb ? bb1 : bg1);
    const float4* W2 = reinterpret_cast<const float4*>(gb ? Wb2 : Wg2);
    const float4* B2 = reinterpret_cast<const float4*>(gb ? bb2 : bg2);
    float* outp = gb ? beta : gamma;

    __shared__ float rs[DD];
    __shared__ float4 hpart[256];
    __shared__ float hid[HD];
    reinterpret_cast<float4*>(rs)[tid] =
        reinterpret_cast<const float4*>(repr)[c * 256 + tid];
    __syncthreads();

    // ---- layer 1: hidden[h] = relu(sum_d rs[d] * W1[d][h] + b1[h])
    {
        int w = tid & 31;        // h4 = w*4
        int kh = tid >> 5;       // 0..7 : d-range [kh*128, kh*128+128)
        const float4* Wp = W1 + (size_t)(kh * 128) * 32 + w;
        const float* rp = rs + kh * 128;
        float4 s = {0.f, 0.f, 0.f, 0.f};
#pragma unroll 8
        for (int d = 0; d < 128; d++) {
            float4 ww = Wp[(size_t)d * 32];
            float rv = rp[d];
            s.x = fmaf(rv, ww.x, s.x);
            s.y = fmaf(rv, ww.y, s.y);
            s.z = fmaf(rv, ww.z, s.z);
            s.w = fmaf(rv, ww.w, s.w);
        }
        hpart[tid] = s;
    }
    __syncthreads();
    if (tid < 32) {
        float4 s = {0.f, 0.f, 0.f, 0.f};
#pragma unroll
        for (int k = 0; k < 8; k++) {
            float4 a = hpart[k * 32 + tid];
            s.x += a.x; s.y += a.y; s.z += a.z; s.w += a.w;
        }
        float4 b = B1[tid];
        hid[tid * 4 + 0] = fmaxf(s.x + b.x, 0.f);
        hid[tid * 4 + 1] = fmaxf(s.y + b.y, 0.f);
        hid[tid * 4 + 2] = fmaxf(s.z + b.z, 0.f);
        hid[tid * 4 + 3] = fmaxf(s.w + b.w, 0.f);
    }
    __syncthreads();

    // ---- layer 2: out[d4] = b2[d4] + sum_h hid[h] * W2[h][d4]
    {
        float4 acc = B2[tid];
        const float4* Wp = W2 + tid;
#pragma unroll 4
        for (int h = 0; h < HD; h++) {
            float4 ww = Wp[(size_t)h * 256];
            float hv = hid[h];
            acc.x = fmaf(hv, ww.x, acc.x);
            acc.y = fmaf(hv, ww.y, acc.y);
            acc.z = fmaf(hv, ww.z, acc.z);
            acc.w = fmaf(hv, ww.w, acc.w);
        }
        reinterpret_cast<float4*>(outp)[c * 256 + tid] = acc;
    }
}

// ============ K3: BN-fold + affine + softmax-mask + mean + l2norm + dot ===
// grid (64 b, 8 cg); block covers full d=1024 (float4/thread) for 4 captions
__global__ __launch_bounds__(256, 2) void kD(const float* __restrict__ img,
                                             const float* __restrict__ gamma,
                                             const float* __restrict__ beta,
                                             const float* __restrict__ capn,
                                             const float* __restrict__ meanp,
                                             const float* __restrict__ rstdp,
                                             float* __restrict__ sims) {
    int b = blockIdx.x, cg = blockIdx.y;
    int tid = threadIdx.x;
    int lane = tid & 63, wid = tid >> 6;
    const float4* ip = reinterpret_cast<const float4*>(img + (size_t)b * RR * DD) + tid;
    float4 x[RR];
#pragma unroll
    for (int r = 0; r < RR; r++) x[r] = ip[(size_t)r * 256];
    float4 mn = reinterpret_cast<const float4*>(meanp)[tid];
    float4 rsd = reinterpret_cast<const float4*>(rstdp)[tid];
    __shared__ float sq_l[4][4], dt_l[4][4];
    const float CEXP = GAMMA_SM * LOG2E;
    for (int ci = 0; ci < 4; ci++) {
        int c = cg * 4 + ci;
        float4 g  = reinterpret_cast<const float4*>(gamma)[c * 256 + tid];
        float4 bt = reinterpret_cast<const float4*>(beta)[c * 256 + tid];
        float4 cn = reinterpret_cast<const float4*>(capn)[c * 256 + tid];
        // fold BN: a = gamma*rstd; bv = beta - mean*a
        float4 a  = {g.x * rsd.x, g.y * rsd.y, g.z * rsd.z, g.w * rsd.w};
        float4 bv = {fmaf(-mn.x, a.x, bt.x), fmaf(-mn.y, a.y, bt.y),
                     fmaf(-mn.z, a.z, bt.z), fmaf(-mn.w, a.w, bt.w)};
        float4 se = {0.f, 0.f, 0.f, 0.f}, so = {0.f, 0.f, 0.f, 0.f};
        // |out*GAMMA| << 88 (0.02-scaled weights): no max-subtract needed
#pragma unroll
        for (int r = 0; r < RR; r++) {
            float4 o;
            o.x = fmaf(a.x, x[r].x, bv.x);
            o.y = fmaf(a.y, x[r].y, bv.y);
            o.z = fmaf(a.z, x[r].z, bv.z);
            o.w = fmaf(a.w, x[r].w, bv.w);
            float ex_ = exp2f(o.x * CEXP);
            float ey = exp2f(o.y * CEXP);
            float ez = exp2f(o.z * CEXP);
            float ew = exp2f(o.w * CEXP);
            se.x += ex_; se.y += ey; se.z += ez; se.w += ew;
            so.x = fmaf(ex_, o.x, so.x);
            so.y = fmaf(ey, o.y, so.y);
            so.z = fmaf(ez, o.z, so.z);
            so.w = fmaf(ew, o.w, so.w);
        }
        const float invR = 1.0f / (float)RR;
        float4 val = {so.x / se.x * invR, so.y / se.y * invR,
                      so.z / se.z * invR, so.w / se.w * invR};
        float sq  = fmaf(val.x, val.x, fmaf(val.y, val.y, fmaf(val.z, val.z, val.w * val.w)));
        float dt  = fmaf(val.x, cn.x, fmaf(val.y, cn.y, fmaf(val.z, cn.z, val.w * cn.w)));
#pragma unroll
        for (int off = 32; off > 0; off >>= 1) {
            sq += __shfl_down(sq, off);
            dt += __shfl_down(dt, off);
        }
        if (lane == 0) { sq_l[wid][ci] = sq; dt_l[wid][ci] = dt; }
    }
    __syncthreads();
    if (tid < 4) {
        float sq = sq_l[0][tid] + sq_l[1][tid] + sq_l[2][tid] + sq_l[3][tid];
        float dt = dt_l[0][tid] + dt_l[1][tid] + dt_l[2][tid] + dt_l[3][tid];
        sims[b * BC + cg * 4 + tid] = dt / (sqrtf(sq) + EPS_L2);
    }
}

extern "C" void kernel_launch(void* const* d_in, const int* in_sizes, int n_in,
                              void* d_out, int out_size, void* d_ws, size_t ws_size,
                              hipStream_t stream) {
    const float* img = (const float*)d_in[0];   // (64,36,1024)
    const float* cap = (const float*)d_in[1];   // (32,64,1024)
    const float* Wg1 = (const float*)d_in[2];   // (1024,128)
    const float* bg1 = (const float*)d_in[3];   // (128,)
    const float* Wg2 = (const float*)d_in[4];   // (128,1024)
    const float* bg2 = (const float*)d_in[5];   // (1024,)
    const float* Wb1 = (const float*)d_in[6];
    const float* bb1 = (const float*)d_in[7];
    const float* Wb2 = (const float*)d_in[8];
    const float* bb2 = (const float*)d_in[9];
    const int* lens = (const int*)d_in[10];
    float* out = (float*)d_out;                 // (64,32)

    float* ws = (float*)d_ws;
    float* repr  = ws;             // 32768
    float* capn  = ws + 32768;     // 32768
    float* meanp = ws + 65536;     // 1024
    float* rstdp = ws + 66560;     // 1024
    float* gamma = ws + 67584;     // 32768
    float* beta  = ws + 100352;    // 32768

    kP<<<64, 256, 0, stream>>>(cap, lens, img, repr, capn, meanp, rstdp);
    kM<<<64, 256, 0, stream>>>(repr, Wg1, bg1, Wg2, bg2, Wb1, bb1, Wb2, bb2,
                               gamma, beta);
    kD<<<dim3(BI, 8), 256, 0, stream>>>(img, gamma, beta, capn, meanp, rstdp, out);
}

// Round 7
// 49.453 us; speedup vs baseline: 1.4338x; 1.4338x over previous
//
#include <hip/hip_runtime.h>
#include <math.h>

#define DD 1024
#define HD 128
#define BI 64
#define RR 36
#define BC 32
#define TT 64

#define EPS_BN 1e-5f
#define EPS_L2 1e-8f
#define GAMMA_SM 10.0f
#define LOG2E 1.44269504088896f

// ===== K1 (1024 blocks, all independent):
//   [0..255]    pc partials (caption mean-pool partials, for capn)
//   [256..511]  BN partial sums over 9-row groups
//   [512..1023] MLP layer-1 partials DIRECTLY from cap (32 c x 16 kc):
//               linearity: hidden_pre = (1/len)*sum_t cap @ W1 slice
__global__ __launch_bounds__(256) void k1(const float* __restrict__ cap,
                                          const int* __restrict__ lens,
                                          const float* __restrict__ img,
                                          const float* __restrict__ Wg1,
                                          const float* __restrict__ Wb1,
                                          float* __restrict__ pc,
                                          float* __restrict__ bnpart,
                                          float* __restrict__ hp) {
    int bid = blockIdx.x, tid = threadIdx.x;
    if (bid < 256) {
        int c = bid >> 3, tg = bid & 7;
        int len = lens[c];
        const float4* p = reinterpret_cast<const float4*>(cap + (size_t)c * TT * DD) + tid;
        float4 s = {0.f, 0.f, 0.f, 0.f};
        int t0 = tg * 8;
#pragma unroll
        for (int i = 0; i < 8; i++) {
            int t = t0 + i;
            if (t < len) {
                float4 x = p[(size_t)t * 256];
                s.x += x.x; s.y += x.y; s.z += x.z; s.w += x.w;
            }
        }
        reinterpret_cast<float4*>(pc)[bid * 256 + tid] = s;
    } else if (bid < 512) {
        int g = bid - 256;   // 0..255, 9 rows each (256*9 = 2304 = BI*RR)
        const float4* p = reinterpret_cast<const float4*>(img) + (size_t)g * 9 * 256 + tid;
        float4 s = {0.f, 0.f, 0.f, 0.f}, q = {0.f, 0.f, 0.f, 0.f};
#pragma unroll
        for (int i = 0; i < 9; i++) {
            float4 x = p[(size_t)i * 256];
            s.x += x.x; s.y += x.y; s.z += x.z; s.w += x.w;
            q.x = fmaf(x.x, x.x, q.x); q.y = fmaf(x.y, x.y, q.y);
            q.z = fmaf(x.z, x.z, q.z); q.w = fmaf(x.w, x.w, q.w);
        }
        float4* bp = reinterpret_cast<float4*>(bnpart);
        bp[(g * 2 + 0) * 256 + tid] = s;
        bp[(g * 2 + 1) * 256 + tid] = q;
    } else {
        int e = bid - 512;          // 0..511
        int c = e >> 4, kc = e & 15;  // d-slice [kc*64, kc*64+64)
        int len = lens[c];
        __shared__ float4 red[16][17];
        __shared__ float rs[64];
        int j = tid & 15, tg = tid >> 4;
        const float4* cp = reinterpret_cast<const float4*>(cap + (size_t)c * TT * DD + kc * 64) + j;
        float4 s = {0.f, 0.f, 0.f, 0.f};
#pragma unroll
        for (int i = 0; i < 4; i++) {
            int t = tg + i * 16;
            if (t < len) {
                float4 x = cp[(size_t)t * 256];
                s.x += x.x; s.y += x.y; s.z += x.z; s.w += x.w;
            }
        }
        red[tg][j] = s;
        __syncthreads();
#pragma unroll
        for (int off = 8; off > 0; off >>= 1) {
            if (tg < off) {
                float4 o = red[tg + off][j];
                red[tg][j].x += o.x; red[tg][j].y += o.y;
                red[tg][j].z += o.z; red[tg][j].w += o.w;
            }
            __syncthreads();
        }
        if (tid < 16) {
            float inv = 1.0f / (float)len;
            float4 v = red[0][tid];
            rs[tid * 4 + 0] = v.x * inv;
            rs[tid * 4 + 1] = v.y * inv;
            rs[tid * 4 + 2] = v.z * inv;
            rs[tid * 4 + 3] = v.w * inv;
        }
        __syncthreads();
        int gb = tid >> 7, h = tid & (HD - 1);
        const float* Wp = (gb ? Wb1 : Wg1) + (size_t)(kc * 64) * HD + h;
        float a0 = 0.f, a1 = 0.f, a2 = 0.f, a3 = 0.f;
#pragma unroll
        for (int d = 0; d < 64; d += 4) {
            a0 = fmaf(rs[d + 0], Wp[(size_t)(d + 0) * HD], a0);
            a1 = fmaf(rs[d + 1], Wp[(size_t)(d + 1) * HD], a1);
            a2 = fmaf(rs[d + 2], Wp[(size_t)(d + 2) * HD], a2);
            a3 = fmaf(rs[d + 3], Wp[(size_t)(d + 3) * HD], a3);
        }
        hp[(size_t)e * 256 + tid] = (a0 + a1) + (a2 + a3);
    }
}

// ===== K2 (320 blocks):
//   [0..31]   capn: reduce pc -> mean-pool -> l2norm
//   [32..63]  mean/rstd: reduce bnpart
//   [64..319] (32 c x 8 dg): reduce hp, +bias, relu, layer-2 -> gamma/beta
__global__ __launch_bounds__(256) void k2(const float* __restrict__ pc,
                                          const int* __restrict__ lens,
                                          const float* __restrict__ bnpart,
                                          const float* __restrict__ hp,
                                          const float* __restrict__ bg1,
                                          const float* __restrict__ bb1,
                                          const float* __restrict__ Wg2,
                                          const float* __restrict__ bg2,
                                          const float* __restrict__ Wb2,
                                          const float* __restrict__ bb2,
                                          float* __restrict__ capn,
                                          float* __restrict__ meanp,
                                          float* __restrict__ rstdp,
                                          float* __restrict__ gamma,
                                          float* __restrict__ beta) {
    int bid = blockIdx.x, tid = threadIdx.x;
    __shared__ float lds[512];
    if (bid < 32) {
        int c = bid;
        const float4* p = reinterpret_cast<const float4*>(pc) + (size_t)c * 8 * 256 + tid;
        float4 s = {0.f, 0.f, 0.f, 0.f};
#pragma unroll
        for (int g = 0; g < 8; g++) {
            float4 x = p[(size_t)g * 256];
            s.x += x.x; s.y += x.y; s.z += x.z; s.w += x.w;
        }
        float inv = 1.0f / (float)lens[c];
        float4 v = {s.x * inv, s.y * inv, s.z * inv, s.w * inv};
        lds[tid] = fmaf(v.x, v.x, fmaf(v.y, v.y, fmaf(v.z, v.z, v.w * v.w)));
        __syncthreads();
        for (int st = 128; st > 0; st >>= 1) {
            if (tid < st) lds[tid] += lds[tid + st];
            __syncthreads();
        }
        float invn = 1.0f / (sqrtf(lds[0]) + EPS_L2);
        float4 o = {v.x * invn, v.y * invn, v.z * invn, v.w * invn};
        reinterpret_cast<float4*>(capn)[c * 256 + tid] = o;
    } else if (bid < 64) {
        int j = bid - 32;
        int dd = tid & 31, gs = tid >> 5;          // 32 d-cols x 8 g-slices
        int d = j * 32 + dd;
        float s = 0.f, q = 0.f;
        for (int g = gs; g < 256; g += 8) {
            s += bnpart[(size_t)(g * 2 + 0) * DD + d];
            q += bnpart[(size_t)(g * 2 + 1) * DD + d];
        }
        lds[gs * 32 + dd] = s;
        lds[256 + gs * 32 + dd] = q;
        __syncthreads();
        if (gs == 0) {
            float ss = 0.f, qq = 0.f;
#pragma unroll
            for (int k = 0; k < 8; k++) {
                ss += lds[k * 32 + dd];
                qq += lds[256 + k * 32 + dd];
            }
            const float invN = 1.0f / (float)(BI * RR);
            float m = ss * invN;
            float var = fmaf(-m, m, qq * invN);
            meanp[d] = m;
            rstdp[d] = rsqrtf(var + EPS_BN);
        }
    } else {
        int e = bid - 64;
        int c = e >> 3, dg = e & 7;
        int gb = tid >> 7, h = tid & (HD - 1);
        const float* hpp = hp + (size_t)c * 16 * 256 + tid;
        float s = 0.f;
#pragma unroll
        for (int k = 0; k < 16; k++) s += hpp[k * 256];
        lds[tid] = fmaxf(s + (gb ? bb1[h] : bg1[h]), 0.f);
        __syncthreads();
        int d = dg * HD + h;
        const float* Wp = (gb ? Wb2 : Wg2) + d;
        const float* hs = lds + gb * HD;
        float a0 = 0.f, a1 = 0.f, a2 = 0.f, a3 = 0.f;
        float a4 = 0.f, a5 = 0.f, a6 = 0.f, a7 = 0.f;
#pragma unroll
        for (int hh = 0; hh < HD; hh += 8) {
            a0 = fmaf(hs[hh + 0], Wp[(size_t)(hh + 0) * DD], a0);
            a1 = fmaf(hs[hh + 1], Wp[(size_t)(hh + 1) * DD], a1);
            a2 = fmaf(hs[hh + 2], Wp[(size_t)(hh + 2) * DD], a2);
            a3 = fmaf(hs[hh + 3], Wp[(size_t)(hh + 3) * DD], a3);
            a4 = fmaf(hs[hh + 4], Wp[(size_t)(hh + 4) * DD], a4);
            a5 = fmaf(hs[hh + 5], Wp[(size_t)(hh + 5) * DD], a5);
            a6 = fmaf(hs[hh + 6], Wp[(size_t)(hh + 6) * DD], a6);
            a7 = fmaf(hs[hh + 7], Wp[(size_t)(hh + 7) * DD], a7);
        }
        float o = ((a0 + a1) + (a2 + a3)) + ((a4 + a5) + (a6 + a7))
                  + (gb ? bb2[d] : bg2[d]);
        (gb ? beta : gamma)[c * DD + d] = o;
    }
}

// ===== K3 (512 blocks): BN-fold + affine + softmax-mask + mean + l2n + dot
__global__ __launch_bounds__(256, 2) void k3(const float* __restrict__ img,
                                             const float* __restrict__ gamma,
                                             const float* __restrict__ beta,
                                             const float* __restrict__ capn,
                                             const float* __restrict__ meanp,
                                             const float* __restrict__ rstdp,
                                             float* __restrict__ sims) {
    int b = blockIdx.x, cg = blockIdx.y;
    int tid = threadIdx.x;
    int lane = tid & 63, wid = tid >> 6;
    const float4* ip = reinterpret_cast<const float4*>(img + (size_t)b * RR * DD) + tid;
    float4 x[RR];
#pragma unroll
    for (int r = 0; r < RR; r++) x[r] = ip[(size_t)r * 256];
    float4 mn = reinterpret_cast<const float4*>(meanp)[tid];
    float4 rsd = reinterpret_cast<const float4*>(rstdp)[tid];
    __shared__ float sq_l[4][4], dt_l[4][4];
    const float CEXP = GAMMA_SM * LOG2E;
    for (int ci = 0; ci < 4; ci++) {
        int c = cg * 4 + ci;
        float4 g  = reinterpret_cast<const float4*>(gamma)[c * 256 + tid];
        float4 bt = reinterpret_cast<const float4*>(beta)[c * 256 + tid];
        float4 cn = reinterpret_cast<const float4*>(capn)[c * 256 + tid];
        float4 a  = {g.x * rsd.x, g.y * rsd.y, g.z * rsd.z, g.w * rsd.w};
        float4 bv = {fmaf(-mn.x, a.x, bt.x), fmaf(-mn.y, a.y, bt.y),
                     fmaf(-mn.z, a.z, bt.z), fmaf(-mn.w, a.w, bt.w)};
        float4 se = {0.f, 0.f, 0.f, 0.f}, so = {0.f, 0.f, 0.f, 0.f};
        // |out*GAMMA| << 88 (0.02-scaled weights): no max-subtract needed
#pragma unroll
        for (int r = 0; r < RR; r++) {
            float4 o;
            o.x = fmaf(a.x, x[r].x, bv.x);
            o.y = fmaf(a.y, x[r].y, bv.y);
            o.z = fmaf(a.z, x[r].z, bv.z);
            o.w = fmaf(a.w, x[r].w, bv.w);
            float ex_ = exp2f(o.x * CEXP);
            float ey = exp2f(o.y * CEXP);
            float ez = exp2f(o.z * CEXP);
            float ew = exp2f(o.w * CEXP);
            se.x += ex_; se.y += ey; se.z += ez; se.w += ew;
            so.x = fmaf(ex_, o.x, so.x);
            so.y = fmaf(ey, o.y, so.y);
            so.z = fmaf(ez, o.z, so.z);
            so.w = fmaf(ew, o.w, so.w);
        }
        const float invR = 1.0f / (float)RR;
        float4 val = {so.x / se.x * invR, so.y / se.y * invR,
                      so.z / se.z * invR, so.w / se.w * invR};
        float sq  = fmaf(val.x, val.x, fmaf(val.y, val.y, fmaf(val.z, val.z, val.w * val.w)));
        float dt  = fmaf(val.x, cn.x, fmaf(val.y, cn.y, fmaf(val.z, cn.z, val.w * cn.w)));
#pragma unroll
        for (int off = 32; off > 0; off >>= 1) {
            sq += __shfl_down(sq, off);
            dt += __shfl_down(dt, off);
        }
        if (lane == 0) { sq_l[wid][ci] = sq; dt_l[wid][ci] = dt; }
    }
    __syncthreads();
    if (tid < 4) {
        float sq = sq_l[0][tid] + sq_l[1][tid] + sq_l[2][tid] + sq_l[3][tid];
        float dt = dt_l[0][tid] + dt_l[1][tid] + dt_l[2][tid] + dt_l[3][tid];
        sims[b * BC + cg * 4 + tid] = dt / (sqrtf(sq) + EPS_L2);
    }
}

extern "C" void kernel_launch(void* const* d_in, const int* in_sizes, int n_in,
                              void* d_out, int out_size, void* d_ws, size_t ws_size,
                              hipStream_t stream) {
    const float* img = (const float*)d_in[0];   // (64,36,1024)
    const float* cap = (const float*)d_in[1];   // (32,64,1024)
    const float* Wg1 = (const float*)d_in[2];   // (1024,128)
    const float* bg1 = (const float*)d_in[3];   // (128,)
    const float* Wg2 = (const float*)d_in[4];   // (128,1024)
    const float* bg2 = (const float*)d_in[5];   // (1024,)
    const float* Wb1 = (const float*)d_in[6];
    const float* bb1 = (const float*)d_in[7];
    const float* Wb2 = (const float*)d_in[8];
    const float* bb2 = (const float*)d_in[9];
    const int* lens = (const int*)d_in[10];
    float* out = (float*)d_out;                 // (64,32)

    float* ws = (float*)d_ws;
    float* pc     = ws;              // 256*1024   = 262144
    float* bnpart = ws + 262144;     // 256*2*1024 = 524288
    float* hp     = ws + 786432;     // 512*256    = 131072
    float* capn   = ws + 917504;     // 32768
    float* meanp  = ws + 950272;     // 1024
    float* rstdp  = ws + 951296;     // 1024
    float* gamma  = ws + 952320;     // 32768
    float* beta   = ws + 985088;     // 32768

    k1<<<1024, 256, 0, stream>>>(cap, lens, img, Wg1, Wb1, pc, bnpart, hp);
    k2<<<320, 256, 0, stream>>>(pc, lens, bnpart, hp, bg1, bb1,
                                Wg2, bg2, Wb2, bb2,
                                capn, meanp, rstdp, gamma, beta);
    k3<<<dim3(BI, 8), 256, 0, stream>>>(img, gamma, beta, capn, meanp, rstdp, out);
}

// Round 8
// 47.527 us; speedup vs baseline: 1.4919x; 1.0405x over previous
//
#include <hip/hip_runtime.h>
#include <math.h>

#define DD 1024
#define HD 128
#define BI 64
#define RR 36
#define BC 32
#define TT 64

#define EPS_BN 1e-5f
#define EPS_L2 1e-8f
#define GAMMA_SM 10.0f
#define LOG2E 1.44269504088896f

// ===== K1 (768 blocks):
//   [0..255]   BN partial sums over 9-row groups of img
//   [256..767] (32 c x 16 kc): cap t-pool for a 64-d slice -> repr slice +
//              partial sq-norm + MLP layer-1 partials (cap read ONCE)
__global__ __launch_bounds__(256) void k1(const float* __restrict__ cap,
                                          const int* __restrict__ lens,
                                          const float* __restrict__ img,
                                          const float* __restrict__ Wg1,
                                          const float* __restrict__ Wb1,
                                          float* __restrict__ bnpart,
                                          float* __restrict__ repr,
                                          float* __restrict__ sqpart,
                                          float* __restrict__ hp) {
    int bid = blockIdx.x, tid = threadIdx.x;
    if (bid < 256) {
        int g = bid;   // 0..255, 9 rows each (256*9 = 2304 = BI*RR)
        const float4* p = reinterpret_cast<const float4*>(img) + (size_t)g * 9 * 256 + tid;
        float4 s = {0.f, 0.f, 0.f, 0.f}, q = {0.f, 0.f, 0.f, 0.f};
#pragma unroll
        for (int i = 0; i < 9; i++) {
            float4 x = p[(size_t)i * 256];
            s.x += x.x; s.y += x.y; s.z += x.z; s.w += x.w;
            q.x = fmaf(x.x, x.x, q.x); q.y = fmaf(x.y, x.y, q.y);
            q.z = fmaf(x.z, x.z, q.z); q.w = fmaf(x.w, x.w, q.w);
        }
        float4* bp = reinterpret_cast<float4*>(bnpart);
        bp[(g * 2 + 0) * 256 + tid] = s;
        bp[(g * 2 + 1) * 256 + tid] = q;
    } else {
        int e = bid - 256;            // 0..511
        int c = e >> 4, kc = e & 15;  // d-slice [kc*64, kc*64+64)
        int len = lens[c];
        __shared__ float4 red[16][17];
        __shared__ float rs[64];
        __shared__ float sqs[16];
        int j = tid & 15, tg = tid >> 4;
        const float4* cp = reinterpret_cast<const float4*>(cap + (size_t)c * TT * DD + kc * 64) + j;
        float4 s = {0.f, 0.f, 0.f, 0.f};
#pragma unroll
        for (int i = 0; i < 4; i++) {
            int t = tg + i * 16;
            if (t < len) {
                float4 x = cp[(size_t)t * 256];
                s.x += x.x; s.y += x.y; s.z += x.z; s.w += x.w;
            }
        }
        red[tg][j] = s;
        __syncthreads();
#pragma unroll
        for (int off = 8; off > 0; off >>= 1) {
            if (tg < off) {
                float4 o = red[tg + off][j];
                red[tg][j].x += o.x; red[tg][j].y += o.y;
                red[tg][j].z += o.z; red[tg][j].w += o.w;
            }
            __syncthreads();
        }
        if (tid < 16) {
            float inv = 1.0f / (float)len;
            float4 v = red[0][tid];
            v.x *= inv; v.y *= inv; v.z *= inv; v.w *= inv;
            rs[tid * 4 + 0] = v.x;
            rs[tid * 4 + 1] = v.y;
            rs[tid * 4 + 2] = v.z;
            rs[tid * 4 + 3] = v.w;
            reinterpret_cast<float4*>(repr)[c * 256 + kc * 16 + tid] = v;
            sqs[tid] = fmaf(v.x, v.x, fmaf(v.y, v.y, fmaf(v.z, v.z, v.w * v.w)));
        }
        __syncthreads();
        if (tid == 0) {
            float s2 = 0.f;
#pragma unroll
            for (int k = 0; k < 16; k++) s2 += sqs[k];
            sqpart[c * 16 + kc] = s2;
        }
        int gb = tid >> 7, h = tid & (HD - 1);
        const float* Wp = (gb ? Wb1 : Wg1) + (size_t)(kc * 64) * HD + h;
        float a0 = 0.f, a1 = 0.f, a2 = 0.f, a3 = 0.f;
#pragma unroll
        for (int d = 0; d < 64; d += 4) {
            a0 = fmaf(rs[d + 0], Wp[(size_t)(d + 0) * HD], a0);
            a1 = fmaf(rs[d + 1], Wp[(size_t)(d + 1) * HD], a1);
            a2 = fmaf(rs[d + 2], Wp[(size_t)(d + 2) * HD], a2);
            a3 = fmaf(rs[d + 3], Wp[(size_t)(d + 3) * HD], a3);
        }
        hp[(size_t)e * 256 + tid] = (a0 + a1) + (a2 + a3);
    }
}

// ===== K2 (320 blocks):
//   [0..31]   capn: repr + sqpart -> l2-normalized caption vector
//   [32..63]  mean/rstd: reduce bnpart
//   [64..319] (32 c x 8 dg): reduce hp, +bias, relu, layer-2 -> gamma/beta
__global__ __launch_bounds__(256) void k2(const float* __restrict__ repr,
                                          const float* __restrict__ sqpart,
                                          const float* __restrict__ bnpart,
                                          const float* __restrict__ hp,
                                          const float* __restrict__ bg1,
                                          const float* __restrict__ bb1,
                                          const float* __restrict__ Wg2,
                                          const float* __restrict__ bg2,
                                          const float* __restrict__ Wb2,
                                          const float* __restrict__ bb2,
                                          float* __restrict__ capn,
                                          float* __restrict__ meanp,
                                          float* __restrict__ rstdp,
                                          float* __restrict__ gamma,
                                          float* __restrict__ beta) {
    int bid = blockIdx.x, tid = threadIdx.x;
    __shared__ float lds[512];
    if (bid < 32) {
        int c = bid;
        if (tid < 16) lds[tid] = sqpart[c * 16 + tid];
        __syncthreads();
        float n2 = 0.f;
#pragma unroll
        for (int k = 0; k < 16; k++) n2 += lds[k];
        float invn = 1.0f / (sqrtf(n2) + EPS_L2);
        float4 v = reinterpret_cast<const float4*>(repr)[c * 256 + tid];
        float4 o = {v.x * invn, v.y * invn, v.z * invn, v.w * invn};
        reinterpret_cast<float4*>(capn)[c * 256 + tid] = o;
    } else if (bid < 64) {
        int j = bid - 32;
        int dd = tid & 31, gs = tid >> 5;          // 32 d-cols x 8 g-slices
        int d = j * 32 + dd;
        float s = 0.f, q = 0.f;
        for (int g = gs; g < 256; g += 8) {
            s += bnpart[(size_t)(g * 2 + 0) * DD + d];
            q += bnpart[(size_t)(g * 2 + 1) * DD + d];
        }
        lds[gs * 32 + dd] = s;
        lds[256 + gs * 32 + dd] = q;
        __syncthreads();
        if (gs == 0) {
            float ss = 0.f, qq = 0.f;
#pragma unroll
            for (int k = 0; k < 8; k++) {
                ss += lds[k * 32 + dd];
                qq += lds[256 + k * 32 + dd];
            }
            const float invN = 1.0f / (float)(BI * RR);
            float m = ss * invN;
            float var = fmaf(-m, m, qq * invN);
            meanp[d] = m;
            rstdp[d] = rsqrtf(var + EPS_BN);
        }
    } else {
        int e = bid - 64;
        int c = e >> 3, dg = e & 7;
        int gb = tid >> 7, h = tid & (HD - 1);
        const float* hpp = hp + (size_t)c * 16 * 256 + tid;
        float s = 0.f;
#pragma unroll
        for (int k = 0; k < 16; k++) s += hpp[k * 256];
        lds[tid] = fmaxf(s + (gb ? bb1[h] : bg1[h]), 0.f);
        __syncthreads();
        int d = dg * HD + h;
        const float* Wp = (gb ? Wb2 : Wg2) + d;
        const float* hs = lds + gb * HD;
        float a0 = 0.f, a1 = 0.f, a2 = 0.f, a3 = 0.f;
        float a4 = 0.f, a5 = 0.f, a6 = 0.f, a7 = 0.f;
#pragma unroll
        for (int hh = 0; hh < HD; hh += 8) {
            a0 = fmaf(hs[hh + 0], Wp[(size_t)(hh + 0) * DD], a0);
            a1 = fmaf(hs[hh + 1], Wp[(size_t)(hh + 1) * DD], a1);
            a2 = fmaf(hs[hh + 2], Wp[(size_t)(hh + 2) * DD], a2);
            a3 = fmaf(hs[hh + 3], Wp[(size_t)(hh + 3) * DD], a3);
            a4 = fmaf(hs[hh + 4], Wp[(size_t)(hh + 4) * DD], a4);
            a5 = fmaf(hs[hh + 5], Wp[(size_t)(hh + 5) * DD], a5);
            a6 = fmaf(hs[hh + 6], Wp[(size_t)(hh + 6) * DD], a6);
            a7 = fmaf(hs[hh + 7], Wp[(size_t)(hh + 7) * DD], a7);
        }
        float o = ((a0 + a1) + (a2 + a3)) + ((a4 + a5) + (a6 + a7))
                  + (gb ? bb2[d] : bg2[d]);
        (gb ? beta : gamma)[c * DD + d] = o;
    }
}

// ===== K3 (512 blocks x 512 thr, float2/thread, 4 waves/SIMD):
//   BN-fold + affine + softmax-mask + mean + l2norm + dot
//   exp-scale folded: e = exp2(fma(a', x, bv')), Sum e*o = so'/CEXP
__global__ __launch_bounds__(512, 4) void k3(const float* __restrict__ img,
                                             const float* __restrict__ gamma,
                                             const float* __restrict__ beta,
                                             const float* __restrict__ capn,
                                             const float* __restrict__ meanp,
                                             const float* __restrict__ rstdp,
                                             float* __restrict__ sims) {
    int b = blockIdx.x, cg = blockIdx.y;
    int tid = threadIdx.x;               // 0..511, one float2 of d
    int lane = tid & 63, wid = tid >> 6; // 8 waves
    const float2* ip = reinterpret_cast<const float2*>(img + (size_t)b * RR * DD) + tid;
    float2 x[RR];
#pragma unroll
    for (int r = 0; r < RR; r++) x[r] = ip[(size_t)r * 512];
    float2 mn = reinterpret_cast<const float2*>(meanp)[tid];
    float2 rsd = reinterpret_cast<const float2*>(rstdp)[tid];
    __shared__ float sq_l[8][4], dt_l[8][4];
    const float CEXP = GAMMA_SM * LOG2E;
    const float invRC = 1.0f / ((float)RR * CEXP);
    for (int ci = 0; ci < 4; ci++) {
        int c = cg * 4 + ci;
        float2 g  = reinterpret_cast<const float2*>(gamma)[c * 512 + tid];
        float2 bt = reinterpret_cast<const float2*>(beta)[c * 512 + tid];
        float2 cn = reinterpret_cast<const float2*>(capn)[c * 512 + tid];
        float ax = g.x * rsd.x, ay = g.y * rsd.y;     // true a
        float apx = ax * CEXP, apy = ay * CEXP;       // a' = a*CEXP
        float bpx = fmaf(-mn.x, ax, bt.x) * CEXP;     // bv' = bv*CEXP
        float bpy = fmaf(-mn.y, ay, bt.y) * CEXP;
        float sex = 0.f, sey = 0.f, sox = 0.f, soy = 0.f;
        // |out*GAMMA| << 88 (0.02-scaled weights): no max-subtract needed
#pragma unroll
        for (int r = 0; r < RR; r++) {
            float ox = fmaf(apx, x[r].x, bpx);        // o' = o*CEXP
            float oy = fmaf(apy, x[r].y, bpy);
            float ex_ = exp2f(ox);
            float ey = exp2f(oy);
            sex += ex_; sey += ey;
            sox = fmaf(ex_, ox, sox);                 // so' = Sum e*o'
            soy = fmaf(ey, oy, soy);
        }
        float vx = sox / sex * invRC;                 // val = so'/(se*RR*CEXP)
        float vy = soy / sey * invRC;
        float sq = fmaf(vx, vx, vy * vy);
        float dt = fmaf(vx, cn.x, vy * cn.y);
#pragma unroll
        for (int off = 32; off > 0; off >>= 1) {
            sq += __shfl_down(sq, off);
            dt += __shfl_down(dt, off);
        }
        if (lane == 0) { sq_l[wid][ci] = sq; dt_l[wid][ci] = dt; }
    }
    __syncthreads();
    if (tid < 4) {
        float sq = 0.f, dt = 0.f;
#pragma unroll
        for (int w = 0; w < 8; w++) { sq += sq_l[w][tid]; dt += dt_l[w][tid]; }
        sims[b * BC + cg * 4 + tid] = dt / (sqrtf(sq) + EPS_L2);
    }
}

extern "C" void kernel_launch(void* const* d_in, const int* in_sizes, int n_in,
                              void* d_out, int out_size, void* d_ws, size_t ws_size,
                              hipStream_t stream) {
    const float* img = (const float*)d_in[0];   // (64,36,1024)
    const float* cap = (const float*)d_in[1];   // (32,64,1024)
    const float* Wg1 = (const float*)d_in[2];   // (1024,128)
    const float* bg1 = (const float*)d_in[3];   // (128,)
    const float* Wg2 = (const float*)d_in[4];   // (128,1024)
    const float* bg2 = (const float*)d_in[5];   // (1024,)
    const float* Wb1 = (const float*)d_in[6];
    const float* bb1 = (const float*)d_in[7];
    const float* Wb2 = (const float*)d_in[8];
    const float* bb2 = (const float*)d_in[9];
    const int* lens = (const int*)d_in[10];
    float* out = (float*)d_out;                 // (64,32)

    float* ws = (float*)d_ws;
    float* bnpart = ws;              // 256*2*1024 = 524288
    float* repr   = ws + 524288;     // 32768
    float* sqpart = ws + 557056;     // 512 (pad 1024)
    float* hp     = ws + 558080;     // 512*256 = 131072
    float* capn   = ws + 689152;     // 32768
    float* meanp  = ws + 721920;     // 1024
    float* rstdp  = ws + 722944;     // 1024
    float* gamma  = ws + 723968;     // 32768
    float* beta   = ws + 756736;     // 32768

    k1<<<768, 256, 0, stream>>>(cap, lens, img, Wg1, Wb1, bnpart, repr, sqpart, hp);
    k2<<<320, 256, 0, stream>>>(repr, sqpart, bnpart, hp, bg1, bb1,
                                Wg2, bg2, Wb2, bb2,
                                capn, meanp, rstdp, gamma, beta);
    k3<<<dim3(BI, 8), 512, 0, stream>>>(img, gamma, beta, capn, meanp, rstdp, out);
}

// Round 9
// 39.515 us; speedup vs baseline: 1.7944x; 1.2028x over previous
//
#include <hip/hip_runtime.h>
#include <math.h>

#define DD 1024
#define HD 128
#define BI 64
#define RR 36
#define BC 32
#define TT 64

#define EPS_BN 1e-5f
#define EPS_L2 1e-8f
#define GAMMA_SM 10.0f
#define LOG2E 1.44269504088896f

#define NBN 64        // BN partial groups
#define ROWS_BN 36    // 64*36 = 2304 = BI*RR

// ===== K1 (576 blocks):
//   [0..511] (32 c x 16 kc): cap t-pool of a 64-d slice -> repr slice +
//            partial sq-norm + MLP layer-1 partials (cap read ONCE)
//   [512..575] BN partial sums over 36-row groups of img
__global__ __launch_bounds__(256) void k1(const float* __restrict__ cap,
                                          const int* __restrict__ lens,
                                          const float* __restrict__ img,
                                          const float* __restrict__ Wg1,
                                          const float* __restrict__ Wb1,
                                          float* __restrict__ bnpart,
                                          float* __restrict__ repr,
                                          float* __restrict__ sqpart,
                                          float* __restrict__ hp) {
    int bid = blockIdx.x, tid = threadIdx.x;
    if (bid < 512) {
        int e = bid;                  // 0..511
        int c = e >> 4, kc = e & 15;  // d-slice [kc*64, kc*64+64)
        int len = lens[c];
        __shared__ float4 red[16][17];
        __shared__ float rs[64];
        __shared__ float sqs[16];
        int j = tid & 15, tg = tid >> 4;
        const float4* cp = reinterpret_cast<const float4*>(cap + (size_t)c * TT * DD + kc * 64) + j;
        float4 s = {0.f, 0.f, 0.f, 0.f};
#pragma unroll
        for (int i = 0; i < 4; i++) {
            int t = tg + i * 16;
            if (t < len) {
                float4 x = cp[(size_t)t * 256];
                s.x += x.x; s.y += x.y; s.z += x.z; s.w += x.w;
            }
        }
        red[tg][j] = s;
        __syncthreads();
#pragma unroll
        for (int off = 8; off > 0; off >>= 1) {
            if (tg < off) {
                float4 o = red[tg + off][j];
                red[tg][j].x += o.x; red[tg][j].y += o.y;
                red[tg][j].z += o.z; red[tg][j].w += o.w;
            }
            __syncthreads();
        }
        if (tid < 16) {
            float inv = 1.0f / (float)len;
            float4 v = red[0][tid];
            v.x *= inv; v.y *= inv; v.z *= inv; v.w *= inv;
            rs[tid * 4 + 0] = v.x;
            rs[tid * 4 + 1] = v.y;
            rs[tid * 4 + 2] = v.z;
            rs[tid * 4 + 3] = v.w;
            reinterpret_cast<float4*>(repr)[c * 256 + kc * 16 + tid] = v;
            sqs[tid] = fmaf(v.x, v.x, fmaf(v.y, v.y, fmaf(v.z, v.z, v.w * v.w)));
        }
        __syncthreads();
        if (tid == 0) {
            float s2 = 0.f;
#pragma unroll
            for (int k = 0; k < 16; k++) s2 += sqs[k];
            sqpart[c * 16 + kc] = s2;
        }
        int gb = tid >> 7, h = tid & (HD - 1);
        const float* Wp = (gb ? Wb1 : Wg1) + (size_t)(kc * 64) * HD + h;
        float a0 = 0.f, a1 = 0.f, a2 = 0.f, a3 = 0.f;
#pragma unroll
        for (int d = 0; d < 64; d += 4) {
            a0 = fmaf(rs[d + 0], Wp[(size_t)(d + 0) * HD], a0);
            a1 = fmaf(rs[d + 1], Wp[(size_t)(d + 1) * HD], a1);
            a2 = fmaf(rs[d + 2], Wp[(size_t)(d + 2) * HD], a2);
            a3 = fmaf(rs[d + 3], Wp[(size_t)(d + 3) * HD], a3);
        }
        hp[(size_t)e * 256 + tid] = (a0 + a1) + (a2 + a3);
    } else {
        int g = bid - 512;   // 0..63, 36 rows each
        const float4* p = reinterpret_cast<const float4*>(img) + (size_t)g * ROWS_BN * 256 + tid;
        float4 s = {0.f, 0.f, 0.f, 0.f}, q = {0.f, 0.f, 0.f, 0.f};
#pragma unroll
        for (int i = 0; i < ROWS_BN; i++) {
            float4 x = p[(size_t)i * 256];
            s.x += x.x; s.y += x.y; s.z += x.z; s.w += x.w;
            q.x = fmaf(x.x, x.x, q.x); q.y = fmaf(x.y, x.y, q.y);
            q.z = fmaf(x.z, x.z, q.z); q.w = fmaf(x.w, x.w, q.w);
        }
        float4* bp = reinterpret_cast<float4*>(bnpart);
        bp[(g * 2 + 0) * 256 + tid] = s;
        bp[(g * 2 + 1) * 256 + tid] = q;
    }
}

// ===== K2 (288 blocks):
//   [0..31]   mean/rstd: reduce 64 bnpart groups
//   [32..287] (32 c x 8 dg): reduce hp, +bias, relu, layer-2 -> gamma/beta
__global__ __launch_bounds__(256) void k2(const float* __restrict__ bnpart,
                                          const float* __restrict__ hp,
                                          const float* __restrict__ bg1,
                                          const float* __restrict__ bb1,
                                          const float* __restrict__ Wg2,
                                          const float* __restrict__ bg2,
                                          const float* __restrict__ Wb2,
                                          const float* __restrict__ bb2,
                                          float* __restrict__ meanp,
                                          float* __restrict__ rstdp,
                                          float* __restrict__ gamma,
                                          float* __restrict__ beta) {
    int bid = blockIdx.x, tid = threadIdx.x;
    __shared__ float lds[512];
    if (bid < 32) {
        int j = bid;
        int dd = tid & 31, gs = tid >> 5;          // 32 d-cols x 8 g-slices
        int d = j * 32 + dd;
        float s = 0.f, q = 0.f;
#pragma unroll
        for (int g = gs; g < NBN; g += 8) {
            s += bnpart[(size_t)(g * 2 + 0) * DD + d];
            q += bnpart[(size_t)(g * 2 + 1) * DD + d];
        }
        lds[gs * 32 + dd] = s;
        lds[256 + gs * 32 + dd] = q;
        __syncthreads();
        if (gs == 0) {
            float ss = 0.f, qq = 0.f;
#pragma unroll
            for (int k = 0; k < 8; k++) {
                ss += lds[k * 32 + dd];
                qq += lds[256 + k * 32 + dd];
            }
            const float invN = 1.0f / (float)(BI * RR);
            float m = ss * invN;
            float var = fmaf(-m, m, qq * invN);
            meanp[d] = m;
            rstdp[d] = rsqrtf(var + EPS_BN);
        }
    } else {
        int e = bid - 32;
        int c = e >> 3, dg = e & 7;
        int gb = tid >> 7, h = tid & (HD - 1);
        const float* hpp = hp + (size_t)c * 16 * 256 + tid;
        float s = 0.f;
#pragma unroll
        for (int k = 0; k < 16; k++) s += hpp[k * 256];
        lds[tid] = fmaxf(s + (gb ? bb1[h] : bg1[h]), 0.f);
        __syncthreads();
        int d = dg * HD + h;
        const float* Wp = (gb ? Wb2 : Wg2) + d;
        const float* hs = lds + gb * HD;
        float a0 = 0.f, a1 = 0.f, a2 = 0.f, a3 = 0.f;
        float a4 = 0.f, a5 = 0.f, a6 = 0.f, a7 = 0.f;
#pragma unroll
        for (int hh = 0; hh < HD; hh += 8) {
            a0 = fmaf(hs[hh + 0], Wp[(size_t)(hh + 0) * DD], a0);
            a1 = fmaf(hs[hh + 1], Wp[(size_t)(hh + 1) * DD], a1);
            a2 = fmaf(hs[hh + 2], Wp[(size_t)(hh + 2) * DD], a2);
            a3 = fmaf(hs[hh + 3], Wp[(size_t)(hh + 3) * DD], a3);
            a4 = fmaf(hs[hh + 4], Wp[(size_t)(hh + 4) * DD], a4);
            a5 = fmaf(hs[hh + 5], Wp[(size_t)(hh + 5) * DD], a5);
            a6 = fmaf(hs[hh + 6], Wp[(size_t)(hh + 6) * DD], a6);
            a7 = fmaf(hs[hh + 7], Wp[(size_t)(hh + 7) * DD], a7);
        }
        float o = ((a0 + a1) + (a2 + a3)) + ((a4 + a5) + (a6 + a7))
                  + (gb ? bb2[d] : bg2[d]);
        (gb ? beta : gamma)[c * DD + d] = o;
    }
}

// ===== K3 (512 blocks x 512 thr): BN-fold + affine + softmax-mask + mean +
//       l2norm + dot (against repr; caption-norm folded in as scalar invn_c)
__global__ __launch_bounds__(512, 4) void k3(const float* __restrict__ img,
                                             const float* __restrict__ gamma,
                                             const float* __restrict__ beta,
                                             const float* __restrict__ repr,
                                             const float* __restrict__ sqpart,
                                             const float* __restrict__ meanp,
                                             const float* __restrict__ rstdp,
                                             float* __restrict__ sims) {
    int b = blockIdx.x, cg = blockIdx.y;
    int tid = threadIdx.x;               // 0..511, one float2 of d
    int lane = tid & 63, wid = tid >> 6; // 8 waves
    __shared__ float invn_l[4];
    if (tid < 64) {                      // invn_c for the block's 4 captions
        float v = sqpart[(cg * 4 + (tid >> 4)) * 16 + (tid & 15)];
#pragma unroll
        for (int off = 8; off > 0; off >>= 1) v += __shfl_down(v, off);
        if ((tid & 15) == 0) invn_l[tid >> 4] = 1.0f / (sqrtf(v) + EPS_L2);
    }
    const float2* ip = reinterpret_cast<const float2*>(img + (size_t)b * RR * DD) + tid;
    float2 x[RR];
#pragma unroll
    for (int r = 0; r < RR; r++) x[r] = ip[(size_t)r * 512];
    float2 mn = reinterpret_cast<const float2*>(meanp)[tid];
    float2 rsd = reinterpret_cast<const float2*>(rstdp)[tid];
    __shared__ float sq_l[8][4], dt_l[8][4];
    const float CEXP = GAMMA_SM * LOG2E;
    const float invRC = 1.0f / ((float)RR * CEXP);
    for (int ci = 0; ci < 4; ci++) {
        int c = cg * 4 + ci;
        float2 g  = reinterpret_cast<const float2*>(gamma)[c * 512 + tid];
        float2 bt = reinterpret_cast<const float2*>(beta)[c * 512 + tid];
        float2 cn = reinterpret_cast<const float2*>(repr)[c * 512 + tid];
        float ax = g.x * rsd.x, ay = g.y * rsd.y;     // true a
        float apx = ax * CEXP, apy = ay * CEXP;       // a' = a*CEXP
        float bpx = fmaf(-mn.x, ax, bt.x) * CEXP;     // bv' = bv*CEXP
        float bpy = fmaf(-mn.y, ay, bt.y) * CEXP;
        float sex = 0.f, sey = 0.f, sox = 0.f, soy = 0.f;
        // |out*GAMMA| << 88 (0.02-scaled weights): no max-subtract needed
#pragma unroll
        for (int r = 0; r < RR; r++) {
            float ox = fmaf(apx, x[r].x, bpx);        // o' = o*CEXP
            float oy = fmaf(apy, x[r].y, bpy);
            float ex_ = exp2f(ox);
            float ey = exp2f(oy);
            sex += ex_; sey += ey;
            sox = fmaf(ex_, ox, sox);                 // so' = Sum e*o'
            soy = fmaf(ey, oy, soy);
        }
        float vx = sox / sex * invRC;                 // val = so'/(se*RR*CEXP)
        float vy = soy / sey * invRC;
        float sq = fmaf(vx, vx, vy * vy);
        float dt = fmaf(vx, cn.x, vy * cn.y);         // dot against repr
#pragma unroll
        for (int off = 32; off > 0; off >>= 1) {
            sq += __shfl_down(sq, off);
            dt += __shfl_down(dt, off);
        }
        if (lane == 0) { sq_l[wid][ci] = sq; dt_l[wid][ci] = dt; }
    }
    __syncthreads();
    if (tid < 4) {
        float sq = 0.f, dt = 0.f;
#pragma unroll
        for (int w = 0; w < 8; w++) { sq += sq_l[w][tid]; dt += dt_l[w][tid]; }
        sims[b * BC + cg * 4 + tid] = dt * invn_l[tid] / (sqrtf(sq) + EPS_L2);
    }
}

extern "C" void kernel_launch(void* const* d_in, const int* in_sizes, int n_in,
                              void* d_out, int out_size, void* d_ws, size_t ws_size,
                              hipStream_t stream) {
    const float* img = (const float*)d_in[0];   // (64,36,1024)
    const float* cap = (const float*)d_in[1];   // (32,64,1024)
    const float* Wg1 = (const float*)d_in[2];   // (1024,128)
    const float* bg1 = (const float*)d_in[3];   // (128,)
    const float* Wg2 = (const float*)d_in[4];   // (128,1024)
    const float* bg2 = (const float*)d_in[5];   // (1024,)
    const float* Wb1 = (const float*)d_in[6];
    const float* bb1 = (const float*)d_in[7];
    const float* Wb2 = (const float*)d_in[8];
    const float* bb2 = (const float*)d_in[9];
    const int* lens = (const int*)d_in[10];
    float* out = (float*)d_out;                 // (64,32)

    float* ws = (float*)d_ws;
    float* bnpart = ws;              // 64*2*1024 = 131072
    float* repr   = ws + 131072;     // 32768
    float* sqpart = ws + 163840;     // 512 (pad 1024)
    float* hp     = ws + 164864;     // 512*256 = 131072
    float* meanp  = ws + 295936;     // 1024
    float* rstdp  = ws + 296960;     // 1024
    float* gamma  = ws + 297984;     // 32768
    float* beta   = ws + 330752;     // 32768

    k1<<<576, 256, 0, stream>>>(cap, lens, img, Wg1, Wb1, bnpart, repr, sqpart, hp);
    k2<<<288, 256, 0, stream>>>(bnpart, hp, bg1, bb1, Wg2, bg2, Wb2, bb2,
                                meanp, rstdp, gamma, beta);
    k3<<<dim3(BI, 8), 512, 0, stream>>>(img, gamma, beta, repr, sqpart,
                                        meanp, rstdp, out);
}